// Round 1
// 1118.401 us; speedup vs baseline: 1.6395x; 1.6395x over previous
//
#include <hip/hip_runtime.h>

#define SPECIES_CAP 128
// params (float) layout in ws: [0..3]=a, [4..7]=c(norm), [8]=p, [9]=d,
// [16..144)=z_f, [144..272)=z^p*d
#define WS_A   0
#define WS_C   4
#define WS_ZF  16
#define WS_ZPD (16 + SPECIES_CAP)

// Binning geometry
#define NB       256          // node-range buckets
#define RSHIFT   12
#define RNODES   4096         // nodes per bucket = 1<<RSHIFT
#define NSUB     4            // sub-streams per bucket (counter decontention)
#define CNT_STRIDE 16         // uints per counter (64 B line padding)

// Pass-1 multisplit geometry: 256 threads x ITER edges/thread
#define ITER     16
#define CHUNK    (ITER / 4)   // float4 chunks per thread
#define TILE     (256 * ITER) // 4096 edges per block

// ws byte layout
#define PARAMS_OFF 0
#define CNT_OFF    4096
#define CNT_BYTES  ((size_t)NB * NSUB * CNT_STRIDE * 4)   // 64 KB
#define PAIRS_OFF  (CNT_OFF + CNT_BYTES)

__global__ void zbl_setup(const float* __restrict__ a_raw,
                          const float* __restrict__ c_raw,
                          const float* __restrict__ p_raw,
                          const float* __restrict__ d_raw,
                          const int* __restrict__ index_to_z,
                          int n_species,
                          float* __restrict__ params)
{
    __shared__ float s_p, s_d;
    int t = threadIdx.x;
    if (t == 0) {
        float a[4], c[4];
        float csum = 0.0f;
        for (int i = 0; i < 4; ++i) {
            a[i] = log1pf(expf(a_raw[i]));          // softplus
            c[i] = log1pf(expf(c_raw[i]));
            csum += c[i];
        }
        for (int i = 0; i < 4; ++i) {
            params[WS_A + i] = a[i];
            params[WS_C + i] = c[i] / csum;
        }
        float p = log1pf(expf(p_raw[0]));
        float d = log1pf(expf(d_raw[0]));
        params[8] = p;
        params[9] = d;
        s_p = p;
        s_d = d;
    }
    __syncthreads();
    float p = s_p, d = s_d;
    for (int s = t; s < n_species && s < SPECIES_CAP; s += blockDim.x) {
        float z = (float)index_to_z[s];
        params[WS_ZF + s]  = z;
        params[WS_ZPD + s] = powf(z, p) * d;        // fold d into the table
    }
}

__device__ __forceinline__ float zbl_energy(
    float dist, float cut, int snd, int rcv,
    const int* __restrict__ node_species,
    const float* s_zf, const float* s_zpd,
    const float* s_a, const float* s_c)
{
    int si = node_species[rcv];
    int sj = node_species[snd];
    float zi = s_zf[si];
    float zj = s_zf[sj];
    float x = cut * zi * zj / (dist + 1e-8f);
    float rzd = dist * (s_zpd[si] + s_zpd[sj]);     // dist*(zi^p+zj^p)*d
    float y = s_c[0] * __expf(-s_a[0] * rzd)
            + s_c[1] * __expf(-s_a[1] * rzd)
            + s_c[2] * __expf(-s_a[2] * rzd)
            + s_c[3] * __expf(-s_a[3] * rzd);
    float sd = dist * (1.0f / 1.5f);
    float u1 = (sd > 1e-8f) ? sd : 1e-8f;
    float u2 = ((1.0f - sd) > 1e-8f) ? (1.0f - sd) : 1e-8f;
    float e_d  = __expf(-1.0f / u1);
    float e_1d = __expf(-1.0f / u2);
    float w = e_1d / (e_1d + e_d);
    return 7.199822675975274f * w * x * y;          // KE/2 folded in
}

// ---- Pass 1: block-level multisplit append into node-range buckets ----
// Each block: LDS histogram over NB buckets -> ONE global atomicAdd per
// (block,bucket) reserves a contiguous segment -> records land contiguous,
// so L2 coalesces them into full-line writes (was: 1 line per 8B record).
__global__ __launch_bounds__(256) void zbl_bin_kernel(
    const float* __restrict__ distances,
    const float* __restrict__ cutoffs,
    const int* __restrict__ senders,
    const int* __restrict__ receivers,
    const int* __restrict__ node_species,
    const float* __restrict__ params,
    unsigned* __restrict__ cnt,
    uint2* __restrict__ pairs,
    int cap,
    float* __restrict__ out,
    int E)
{
    __shared__ float s_zf[SPECIES_CAP];
    __shared__ float s_zpd[SPECIES_CAP];
    __shared__ float s_a[4];
    __shared__ float s_c[4];
    __shared__ unsigned h_cnt[NB];    // phase A: histogram, phase C: cursor
    __shared__ unsigned h_base[NB];   // reserved global base per bucket
    int t = threadIdx.x;
    if (t < 4)              s_a[t]     = params[WS_A + t];
    else if (t < 8)         s_c[t - 4] = params[WS_C + (t - 4)];
    for (int s = t; s < SPECIES_CAP; s += 256) {
        s_zf[s]  = params[WS_ZF + s];
        s_zpd[s] = params[WS_ZPD + s];
    }
    for (int s = t; s < NB; s += 256) h_cnt[s] = 0u;
    __syncthreads();

    float en[ITER];
    int   rc[ITER];
    int sub = blockIdx.x & (NSUB - 1);

    // ---- Phase A: compute energies + LDS histogram ----
#pragma unroll
    for (int c = 0; c < CHUNK; ++c) {
        int vbase = (blockIdx.x * (256 * CHUNK) + c * 256 + t) * 4;
        if (vbase + 4 <= E) {
            float4 d4 = *(const float4*)(distances + vbase);
            float4 c4 = *(const float4*)(cutoffs + vbase);
            int4   s4 = *(const int4*)(senders + vbase);
            int4   r4 = *(const int4*)(receivers + vbase);
            int   sn[4] = { s4.x, s4.y, s4.z, s4.w };
            int   rr[4] = { r4.x, r4.y, r4.z, r4.w };
            float dd[4] = { d4.x, d4.y, d4.z, d4.w };
            float cc[4] = { c4.x, c4.y, c4.z, c4.w };
#pragma unroll
            for (int k = 0; k < 4; ++k) {
                rc[c * 4 + k] = rr[k];
                en[c * 4 + k] = zbl_energy(dd[k], cc[k], sn[k], rr[k],
                                           node_species, s_zf, s_zpd, s_a, s_c);
            }
#pragma unroll
            for (int k = 0; k < 4; ++k)
                atomicAdd(&h_cnt[((unsigned)rr[k]) >> RSHIFT], 1u);
        } else {
#pragma unroll
            for (int k = 0; k < 4; ++k) {
                int e = vbase + k;
                if (e < E) {
                    int rcv = receivers[e];
                    rc[c * 4 + k] = rcv;
                    en[c * 4 + k] = zbl_energy(distances[e], cutoffs[e],
                                               senders[e], rcv,
                                               node_species, s_zf, s_zpd,
                                               s_a, s_c);
                    atomicAdd(&h_cnt[((unsigned)rcv) >> RSHIFT], 1u);
                } else {
                    rc[c * 4 + k] = -1;
                }
            }
        }
    }
    __syncthreads();

    // ---- Phase B: reserve contiguous segments (1 atomic per block-bucket) ----
    {
        unsigned n = h_cnt[t];          // NB == blockDim.x == 256
        h_base[t] = n ? atomicAdd(&cnt[(t * NSUB + sub) * CNT_STRIDE], n) : 0u;
        h_cnt[t] = 0u;                  // becomes the scatter cursor
    }
    __syncthreads();

    // ---- Phase C: scatter into this block's private segments ----
#pragma unroll
    for (int k = 0; k < ITER; ++k) {
        if (rc[k] >= 0) {
            unsigned b = ((unsigned)rc[k]) >> RSHIFT;
            unsigned pos = h_base[b] + atomicAdd(&h_cnt[b], 1u);
            if (pos < (unsigned)cap)
                pairs[(size_t)(b * NSUB + sub) * cap + pos] =
                    make_uint2((unsigned)rc[k], __float_as_uint(en[k]));
            else
                unsafeAtomicAdd(out + rc[k], en[k]);   // overflow fallback
        }
    }
}

// ---- Pass 2: one block per bucket; LDS reduce; plain coalesced flush ----
// Buckets partition node space -> single writer per node -> no global atomics
// on the flush (out may hold pass-1 overflow adds, so += not =).
__global__ __launch_bounds__(1024) void zbl_reduce_kernel(
    const unsigned* __restrict__ cnt,
    const uint2* __restrict__ pairs,
    int cap,
    float* __restrict__ out,
    int n_nodes)
{
    __shared__ float acc[RNODES];          // 16 KB
    int b = blockIdx.x;
    int t = threadIdx.x;
    for (int i = t; i < RNODES; i += 1024) acc[i] = 0.0f;
    __syncthreads();

    for (int sub = 0; sub < NSUB; ++sub) {
        int bs = b * NSUB + sub;
        int entries = min((int)cnt[bs * CNT_STRIDE], cap);
        const uint2* pb = pairs + (size_t)bs * cap;
        const uint4* pb4 = (const uint4*)pb;   // cap forced even -> aligned
        int n2 = entries >> 1;
        for (int j = t; j < n2; j += 1024) {
            uint4 q = pb4[j];
            atomicAdd(&acc[q.x & (RNODES - 1)], __uint_as_float(q.y));
            atomicAdd(&acc[q.z & (RNODES - 1)], __uint_as_float(q.w));
        }
        if ((entries & 1) && t == 0) {
            uint2 pr = pb[entries - 1];
            atomicAdd(&acc[pr.x & (RNODES - 1)], __uint_as_float(pr.y));
        }
    }
    __syncthreads();

    int nbase = b << RSHIFT;
    int nmax  = n_nodes - nbase;
    if (nmax <= 0) return;
    if (nmax >= RNODES) {
        float4* o4 = (float4*)(out + nbase);
        const float4* a4 = (const float4*)acc;
        for (int i = t; i < RNODES / 4; i += 1024) {
            float4 v = a4[i];
            float4 o = o4[i];
            o.x += v.x; o.y += v.y; o.z += v.z; o.w += v.w;
            o4[i] = o;
        }
    } else {
        for (int i = t; i < nmax; i += 1024)
            out[nbase + i] += acc[i];
    }
}

// ---- Fallback: direct scattered atomics (R1 behavior) ----
__global__ __launch_bounds__(256) void zbl_direct_kernel(
    const float* __restrict__ distances,
    const float* __restrict__ cutoffs,
    const int* __restrict__ senders,
    const int* __restrict__ receivers,
    const int* __restrict__ node_species,
    const float* __restrict__ params,
    float* __restrict__ out,
    int E)
{
    __shared__ float s_zf[SPECIES_CAP];
    __shared__ float s_zpd[SPECIES_CAP];
    __shared__ float s_a[4];
    __shared__ float s_c[4];
    int t = threadIdx.x;
    if (t < 4)              s_a[t]     = params[WS_A + t];
    else if (t < 8)         s_c[t - 4] = params[WS_C + (t - 4)];
    for (int s = t; s < SPECIES_CAP; s += blockDim.x) {
        s_zf[s]  = params[WS_ZF + s];
        s_zpd[s] = params[WS_ZPD + s];
    }
    __syncthreads();
    int base = (blockIdx.x * 256 + t) * 4;
    int lim = min(base + 4, E);
    for (int e = base; e < lim; ++e) {
        int rcv = receivers[e];
        float en = zbl_energy(distances[e], cutoffs[e], senders[e], rcv,
                              node_species, s_zf, s_zpd, s_a, s_c);
        unsafeAtomicAdd(out + rcv, en);
    }
}

extern "C" void kernel_launch(void* const* d_in, const int* in_sizes, int n_in,
                              void* d_out, int out_size, void* d_ws, size_t ws_size,
                              hipStream_t stream)
{
    const int*   node_species = (const int*)d_in[0];
    const float* distances    = (const float*)d_in[1];
    const float* cutoffs      = (const float*)d_in[2];
    const int*   senders      = (const int*)d_in[3];
    const int*   receivers    = (const int*)d_in[4];
    const int*   index_to_z   = (const int*)d_in[5];
    const float* a_raw        = (const float*)d_in[6];
    const float* c_raw        = (const float*)d_in[7];
    const float* p_raw        = (const float*)d_in[8];
    const float* d_raw        = (const float*)d_in[9];

    int E         = in_sizes[1];
    int n_species = in_sizes[5];
    int n_nodes   = in_sizes[0];
    float*    out    = (float*)d_out;
    float*    params = (float*)((char*)d_ws + PARAMS_OFF);
    unsigned* cnt    = (unsigned*)((char*)d_ws + CNT_OFF);
    uint2*    pairs  = (uint2*)((char*)d_ws + PAIRS_OFF);

    // Sub-stream capacity from available workspace. avg per sub-stream =
    // E/(NB*NSUB) = 31250 for E=32M; ~40000 gives ~28% headroom (variance of
    // per-block reservation is tiny); overflow edges take the direct path.
    size_t avail = (ws_size > PAIRS_OFF) ? (ws_size - PAIRS_OFF) : 0;
    long long cap_ll = (long long)(avail / ((size_t)NB * NSUB * sizeof(uint2)));
    int want = E / (NB * NSUB) + E / (NB * NSUB * 4) + 1024;  // ~1.28x avg
    int cap = (int)((cap_ll < (long long)want) ? cap_ll : (long long)want);
    cap &= ~1;   // even -> uint4-aligned sub-stream bases in pass 2

    hipMemsetAsync(d_out, 0, (size_t)out_size * sizeof(float), stream);
    zbl_setup<<<1, 128, 0, stream>>>(a_raw, c_raw, p_raw, d_raw,
                                     index_to_z, n_species, params);

    if (cap >= 4096) {
        hipMemsetAsync(cnt, 0, CNT_BYTES, stream);
        int blocks = (E + TILE - 1) / TILE;
        zbl_bin_kernel<<<blocks, 256, 0, stream>>>(
            distances, cutoffs, senders, receivers, node_species,
            params, cnt, pairs, cap, out, E);
        zbl_reduce_kernel<<<NB, 1024, 0, stream>>>(
            cnt, pairs, cap, out, n_nodes);
    } else {
        int blocks = ((E + 3) / 4 + 255) / 256;
        zbl_direct_kernel<<<blocks, 256, 0, stream>>>(
            distances, cutoffs, senders, receivers, node_species,
            params, out, E);
    }
}

// Round 2
// 1035.197 us; speedup vs baseline: 1.7712x; 1.0804x over previous
//
#include <hip/hip_runtime.h>

#define SPECIES_CAP 128
// params (float) layout in ws: [0..3]=a, [4..7]=c(norm), [8]=p, [9]=d,
// [16..144)=z_f, [144..272)=z^p*d
#define WS_A   0
#define WS_C   4
#define WS_ZF  16
#define WS_ZPD (16 + SPECIES_CAP)

// Binning geometry
#define NB       256          // node-range buckets
#define RSHIFT   12
#define RNODES   4096         // nodes per bucket = 1<<RSHIFT
#define NSUB     4            // sub-streams per bucket (counter decontention)
#define CNT_STRIDE 16         // uints per counter (64 B line padding)

// Pass-1 multisplit geometry: 256 threads x ITER edges/thread
#define ITER     16
#define CHUNK    (ITER / 4)   // float4 chunks per thread
#define TILE     (256 * ITER) // 4096 edges per block

// ws byte layout
#define PARAMS_OFF 0
#define CNT_OFF    4096
#define CNT_BYTES  ((size_t)NB * NSUB * CNT_STRIDE * 4)   // 64 KB
#define PAIRS_OFF  (CNT_OFF + CNT_BYTES)

__global__ void zbl_setup(const float* __restrict__ a_raw,
                          const float* __restrict__ c_raw,
                          const float* __restrict__ p_raw,
                          const float* __restrict__ d_raw,
                          const int* __restrict__ index_to_z,
                          int n_species,
                          float* __restrict__ params)
{
    __shared__ float s_p, s_d;
    int t = threadIdx.x;
    if (t == 0) {
        float a[4], c[4];
        float csum = 0.0f;
        for (int i = 0; i < 4; ++i) {
            a[i] = log1pf(expf(a_raw[i]));          // softplus
            c[i] = log1pf(expf(c_raw[i]));
            csum += c[i];
        }
        for (int i = 0; i < 4; ++i) {
            params[WS_A + i] = a[i];
            params[WS_C + i] = c[i] / csum;
        }
        float p = log1pf(expf(p_raw[0]));
        float d = log1pf(expf(d_raw[0]));
        params[8] = p;
        params[9] = d;
        s_p = p;
        s_d = d;
    }
    __syncthreads();
    float p = s_p, d = s_d;
    for (int s = t; s < n_species && s < SPECIES_CAP; s += blockDim.x) {
        float z = (float)index_to_z[s];
        params[WS_ZF + s]  = z;
        params[WS_ZPD + s] = powf(z, p) * d;        // fold d into the table
    }
}

__device__ __forceinline__ float zbl_energy(
    float dist, float cut, int snd, int rcv,
    const int* __restrict__ node_species,
    const float* s_zf, const float* s_zpd,
    const float* s_a, const float* s_c)
{
    int si = node_species[rcv];
    int sj = node_species[snd];
    float zi = s_zf[si];
    float zj = s_zf[sj];
    float x = cut * zi * zj / (dist + 1e-8f);
    float rzd = dist * (s_zpd[si] + s_zpd[sj]);     // dist*(zi^p+zj^p)*d
    float y = s_c[0] * __expf(-s_a[0] * rzd)
            + s_c[1] * __expf(-s_a[1] * rzd)
            + s_c[2] * __expf(-s_a[2] * rzd)
            + s_c[3] * __expf(-s_a[3] * rzd);
    float sd = dist * (1.0f / 1.5f);
    float u1 = (sd > 1e-8f) ? sd : 1e-8f;
    float u2 = ((1.0f - sd) > 1e-8f) ? (1.0f - sd) : 1e-8f;
    float e_d  = __expf(-1.0f / u1);
    float e_1d = __expf(-1.0f / u2);
    float w = e_1d / (e_1d + e_d);
    return 7.199822675975274f * w * x * y;          // KE/2 folded in
}

// ---- Pass 1: block-level counting-sort multisplit ----
// Phase A: compute energies; LDS histogram gives each record its rank.
// Phase B: exclusive scan of bucket counts + ONE global atomic per
//          (block,bucket) reserves a contiguous segment.
// Phase C: scatter records bucket-ordered into LDS staging.
// Phase D: linear write-out -> consecutive lanes hit consecutive global
//          addresses (runs of ~16 records) -> stores coalesce, lines are
//          fully covered (no write-allocate RMW).
__global__ __launch_bounds__(256) void zbl_bin_kernel(
    const float* __restrict__ distances,
    const float* __restrict__ cutoffs,
    const int* __restrict__ senders,
    const int* __restrict__ receivers,
    const int* __restrict__ node_species,
    const float* __restrict__ params,
    unsigned* __restrict__ cnt,
    uint2* __restrict__ pairs,
    int cap,
    float* __restrict__ out,
    int E)
{
    __shared__ float s_zf[SPECIES_CAP];
    __shared__ float s_zpd[SPECIES_CAP];
    __shared__ float s_a[4];
    __shared__ float s_c[4];
    __shared__ unsigned h_cnt[NB];     // histogram
    __shared__ unsigned h_lbase[NB];   // local exclusive base (scan)
    __shared__ unsigned h_gbase[NB];   // reserved global segment base
    __shared__ unsigned wtot[4];       // per-wave scan totals
    __shared__ unsigned s_total;
    __shared__ uint2 stg[TILE];        // 32 KB bucket-ordered staging
    int t = threadIdx.x;
    if (t < 4)              s_a[t]     = params[WS_A + t];
    else if (t < 8)         s_c[t - 4] = params[WS_C + (t - 4)];
    for (int s = t; s < SPECIES_CAP; s += 256) {
        s_zf[s]  = params[WS_ZF + s];
        s_zpd[s] = params[WS_ZPD + s];
    }
    h_cnt[t] = 0u;
    __syncthreads();

    float    en[ITER];
    unsigned pk[ITER];                 // (rank<<20) | rcv
    unsigned vmask = 0u;
    int sub = blockIdx.x & (NSUB - 1);

    // ---- Phase A: compute energies + histogram (rank from atomic) ----
#pragma unroll
    for (int c = 0; c < CHUNK; ++c) {
        int vbase = (blockIdx.x * (256 * CHUNK) + c * 256 + t) * 4;
        if (vbase + 4 <= E) {
            float4 d4 = *(const float4*)(distances + vbase);
            float4 c4 = *(const float4*)(cutoffs + vbase);
            int4   s4 = *(const int4*)(senders + vbase);
            int4   r4 = *(const int4*)(receivers + vbase);
            int   sn[4] = { s4.x, s4.y, s4.z, s4.w };
            int   rr[4] = { r4.x, r4.y, r4.z, r4.w };
            float dd[4] = { d4.x, d4.y, d4.z, d4.w };
            float cc[4] = { c4.x, c4.y, c4.z, c4.w };
#pragma unroll
            for (int k = 0; k < 4; ++k)
                en[c * 4 + k] = zbl_energy(dd[k], cc[k], sn[k], rr[k],
                                           node_species, s_zf, s_zpd, s_a, s_c);
#pragma unroll
            for (int k = 0; k < 4; ++k) {
                unsigned b  = ((unsigned)rr[k]) >> RSHIFT;
                unsigned rk = atomicAdd(&h_cnt[b], 1u);
                pk[c * 4 + k] = (rk << 20) | (unsigned)rr[k];
                vmask |= 1u << (c * 4 + k);
            }
        } else {
#pragma unroll
            for (int k = 0; k < 4; ++k) {
                int e = vbase + k;
                if (e < E) {
                    int rcv = receivers[e];
                    en[c * 4 + k] = zbl_energy(distances[e], cutoffs[e],
                                               senders[e], rcv,
                                               node_species, s_zf, s_zpd,
                                               s_a, s_c);
                    unsigned b  = ((unsigned)rcv) >> RSHIFT;
                    unsigned rk = atomicAdd(&h_cnt[b], 1u);
                    pk[c * 4 + k] = (rk << 20) | (unsigned)rcv;
                    vmask |= 1u << (c * 4 + k);
                }
            }
        }
    }
    __syncthreads();

    // ---- Phase B: exclusive scan over NB=256 buckets + global reserve ----
    {
        unsigned orig = h_cnt[t];
        unsigned v = orig;
        int lane = t & 63;
#pragma unroll
        for (int d = 1; d < 64; d <<= 1) {
            unsigned nv = __shfl_up(v, d, 64);
            if (lane >= d) v += nv;
        }
        if (lane == 63) wtot[t >> 6] = v;
        __syncthreads();
        unsigned off = 0;
        int wid = t >> 6;
#pragma unroll
        for (int w = 0; w < 3; ++w)
            if (w < wid) off += wtot[w];
        unsigned incl = off + v;
        h_lbase[t] = incl - orig;
        h_gbase[t] = orig
            ? atomicAdd(&cnt[(t * NSUB + sub) * CNT_STRIDE], orig) : 0u;
        if (t == 255) s_total = incl;
    }
    __syncthreads();

    // ---- Phase C: scatter bucket-ordered into LDS staging ----
#pragma unroll
    for (int k = 0; k < ITER; ++k) {
        if ((vmask >> k) & 1u) {
            unsigned u   = pk[k];
            unsigned rcv = u & 0xFFFFFu;
            unsigned rk  = u >> 20;
            unsigned b   = rcv >> RSHIFT;
            stg[h_lbase[b] + rk] = make_uint2(rcv, __float_as_uint(en[k]));
        }
    }
    __syncthreads();

    // ---- Phase D: linear coalesced write-out ----
    unsigned total = s_total;
    for (unsigned i = t; i < total; i += 256) {
        uint2 q = stg[i];
        unsigned b   = q.x >> RSHIFT;
        unsigned pos = h_gbase[b] + (i - h_lbase[b]);
        if (pos < (unsigned)cap)
            pairs[(size_t)(b * NSUB + sub) * cap + pos] = q;
        else
            unsafeAtomicAdd(out + q.x, __uint_as_float(q.y));  // overflow
    }
}

// ---- Pass 2: one block per sub-stream; LDS reduce; atomic flush ----
// 4 sub-streams share a node range -> flush needs atomics (also covers
// pass-1 overflow adds), but waves flush consecutive nodes so the atomics
// are line-coalesced with at most 4-way contention.
__global__ __launch_bounds__(256) void zbl_reduce_kernel(
    const unsigned* __restrict__ cnt,
    const uint2* __restrict__ pairs,
    int cap,
    float* __restrict__ out,
    int n_nodes)
{
    __shared__ float acc[RNODES];          // 16 KB
    int bs = blockIdx.x;                   // sub-stream id = b*NSUB+sub
    int b  = bs / NSUB;
    int t  = threadIdx.x;
    for (int i = t; i < RNODES; i += 256) acc[i] = 0.0f;
    __syncthreads();

    int entries = min((int)cnt[bs * CNT_STRIDE], cap);
    const uint2* pb  = pairs + (size_t)bs * cap;
    const uint4* pb4 = (const uint4*)pb;   // cap forced even -> aligned
    int n2 = entries >> 1;
    for (int j = t; j < n2; j += 256) {
        uint4 q = pb4[j];
        atomicAdd(&acc[q.x & (RNODES - 1)], __uint_as_float(q.y));
        atomicAdd(&acc[q.z & (RNODES - 1)], __uint_as_float(q.w));
    }
    if ((entries & 1) && t == 0) {
        uint2 pr = pb[entries - 1];
        atomicAdd(&acc[pr.x & (RNODES - 1)], __uint_as_float(pr.y));
    }
    __syncthreads();

    int nbase = b << RSHIFT;
    int nmax  = n_nodes - nbase;
    if (nmax <= 0) return;
    int lim = (nmax < RNODES) ? nmax : RNODES;
    for (int i = t; i < lim; i += 256) {
        float v = acc[i];
        if (v != 0.0f) unsafeAtomicAdd(out + nbase + i, v);
    }
}

// ---- Fallback: direct scattered atomics ----
__global__ __launch_bounds__(256) void zbl_direct_kernel(
    const float* __restrict__ distances,
    const float* __restrict__ cutoffs,
    const int* __restrict__ senders,
    const int* __restrict__ receivers,
    const int* __restrict__ node_species,
    const float* __restrict__ params,
    float* __restrict__ out,
    int E)
{
    __shared__ float s_zf[SPECIES_CAP];
    __shared__ float s_zpd[SPECIES_CAP];
    __shared__ float s_a[4];
    __shared__ float s_c[4];
    int t = threadIdx.x;
    if (t < 4)              s_a[t]     = params[WS_A + t];
    else if (t < 8)         s_c[t - 4] = params[WS_C + (t - 4)];
    for (int s = t; s < SPECIES_CAP; s += blockDim.x) {
        s_zf[s]  = params[WS_ZF + s];
        s_zpd[s] = params[WS_ZPD + s];
    }
    __syncthreads();
    int base = (blockIdx.x * 256 + t) * 4;
    int lim = min(base + 4, E);
    for (int e = base; e < lim; ++e) {
        int rcv = receivers[e];
        float en = zbl_energy(distances[e], cutoffs[e], senders[e], rcv,
                              node_species, s_zf, s_zpd, s_a, s_c);
        unsafeAtomicAdd(out + rcv, en);
    }
}

extern "C" void kernel_launch(void* const* d_in, const int* in_sizes, int n_in,
                              void* d_out, int out_size, void* d_ws, size_t ws_size,
                              hipStream_t stream)
{
    const int*   node_species = (const int*)d_in[0];
    const float* distances    = (const float*)d_in[1];
    const float* cutoffs      = (const float*)d_in[2];
    const int*   senders      = (const int*)d_in[3];
    const int*   receivers    = (const int*)d_in[4];
    const int*   index_to_z   = (const int*)d_in[5];
    const float* a_raw        = (const float*)d_in[6];
    const float* c_raw        = (const float*)d_in[7];
    const float* p_raw        = (const float*)d_in[8];
    const float* d_raw        = (const float*)d_in[9];

    int E         = in_sizes[1];
    int n_species = in_sizes[5];
    int n_nodes   = in_sizes[0];
    float*    out    = (float*)d_out;
    float*    params = (float*)((char*)d_ws + PARAMS_OFF);
    unsigned* cnt    = (unsigned*)((char*)d_ws + CNT_OFF);
    uint2*    pairs  = (uint2*)((char*)d_ws + PAIRS_OFF);

    // Sub-stream capacity from available workspace. avg per sub-stream =
    // E/(NB*NSUB) = 31250 for E=32M; ~40000 gives ~28% headroom; overflow
    // records take the direct-atomic path.
    size_t avail = (ws_size > PAIRS_OFF) ? (ws_size - PAIRS_OFF) : 0;
    long long cap_ll = (long long)(avail / ((size_t)NB * NSUB * sizeof(uint2)));
    int want = E / (NB * NSUB) + E / (NB * NSUB * 4) + 1024;  // ~1.28x avg
    int cap = (int)((cap_ll < (long long)want) ? cap_ll : (long long)want);
    cap &= ~1;   // even -> uint4-aligned sub-stream reads in pass 2

    hipMemsetAsync(d_out, 0, (size_t)out_size * sizeof(float), stream);
    zbl_setup<<<1, 128, 0, stream>>>(a_raw, c_raw, p_raw, d_raw,
                                     index_to_z, n_species, params);

    // rank/rcv packing in pass 1 needs rcv < 2^20
    if (cap >= 4096 && n_nodes <= (1 << 20)) {
        hipMemsetAsync(cnt, 0, CNT_BYTES, stream);
        int blocks = (E + TILE - 1) / TILE;
        zbl_bin_kernel<<<blocks, 256, 0, stream>>>(
            distances, cutoffs, senders, receivers, node_species,
            params, cnt, pairs, cap, out, E);
        zbl_reduce_kernel<<<NB * NSUB, 256, 0, stream>>>(
            cnt, pairs, cap, out, n_nodes);
    } else {
        int blocks = ((E + 3) / 4 + 255) / 256;
        zbl_direct_kernel<<<blocks, 256, 0, stream>>>(
            distances, cutoffs, senders, receivers, node_species,
            params, out, E);
    }
}

// Round 3
// 908.674 us; speedup vs baseline: 2.0179x; 1.1392x over previous
//
#include <hip/hip_runtime.h>

#define SPECIES_CAP 128
// params (float) layout in ws: [0..3]=a, [4..7]=c(norm), [8]=p, [9]=d,
// [16..144)=z_f, [144..272)=z^p*d
#define WS_A   0
#define WS_C   4
#define WS_ZF  16
#define WS_ZPD (16 + SPECIES_CAP)

// Binning geometry
#define NB       256          // node-range buckets
#define RSHIFT   12
#define RNODES   4096         // nodes per bucket = 1<<RSHIFT
#define NSUB     4            // sub-streams per bucket (counter decontention)
#define CNT_STRIDE 16         // uints per counter (64 B line padding)

// Pass-1 multisplit geometry: 512 threads x ITER=8 edges/thread
#define BTHREADS 512
#define ITER     8
#define CHUNK    (ITER / 4)        // float4 chunks per thread
#define TILE     (BTHREADS * ITER) // 4096 edges per block

// ws byte layout (pairs offset is runtime: after u8 species table)
#define PARAMS_OFF 0
#define CNT_OFF    4096
#define CNT_BYTES  ((size_t)NB * NSUB * CNT_STRIDE * 4)   // 64 KB

__global__ void zbl_setup(const float* __restrict__ a_raw,
                          const float* __restrict__ c_raw,
                          const float* __restrict__ p_raw,
                          const float* __restrict__ d_raw,
                          const int* __restrict__ index_to_z,
                          int n_species,
                          float* __restrict__ params)
{
    __shared__ float s_p, s_d;
    int t = threadIdx.x;
    if (t == 0) {
        float a[4], c[4];
        float csum = 0.0f;
        for (int i = 0; i < 4; ++i) {
            a[i] = log1pf(expf(a_raw[i]));          // softplus
            c[i] = log1pf(expf(c_raw[i]));
            csum += c[i];
        }
        for (int i = 0; i < 4; ++i) {
            params[WS_A + i] = a[i];
            params[WS_C + i] = c[i] / csum;
        }
        float p = log1pf(expf(p_raw[0]));
        float d = log1pf(expf(d_raw[0]));
        params[8] = p;
        params[9] = d;
        s_p = p;
        s_d = d;
    }
    __syncthreads();
    float p = s_p, d = s_d;
    for (int s = t; s < n_species && s < SPECIES_CAP; s += blockDim.x) {
        float z = (float)index_to_z[s];
        params[WS_ZF + s]  = z;
        params[WS_ZPD + s] = powf(z, p) * d;        // fold d into the table
    }
}

// Pack node_species (int32, values < 128) into a u8 table: gather working
// set 4 MB -> 1 MB, much better L2 residency for the random per-edge gathers.
__global__ __launch_bounds__(256) void zbl_pack8(
    const int* __restrict__ ns, unsigned char* __restrict__ sp8, int n)
{
    int i4 = (blockIdx.x * 256 + threadIdx.x) * 4;
    if (i4 + 4 <= n) {
        int4 v = *(const int4*)(ns + i4);
        *(uchar4*)(sp8 + i4) = make_uchar4((unsigned char)v.x,
                                           (unsigned char)v.y,
                                           (unsigned char)v.z,
                                           (unsigned char)v.w);
    } else {
        for (int j = i4; j < n; ++j) sp8[j] = (unsigned char)ns[j];
    }
}

// Energy with pre-gathered species; fast rcp (~1 ulp) replaces 4 exact divides.
__device__ __forceinline__ float zbl_energy2(
    float dist, float cut, int si, int sj,
    const float* s_zf, const float* s_zpd,
    const float* s_a, const float* s_c)
{
    float zi = s_zf[si];
    float zj = s_zf[sj];
    float x = cut * zi * zj * __builtin_amdgcn_rcpf(dist + 1e-8f);
    float rzd = dist * (s_zpd[si] + s_zpd[sj]);     // dist*(zi^p+zj^p)*d
    float y = s_c[0] * __expf(-s_a[0] * rzd)
            + s_c[1] * __expf(-s_a[1] * rzd)
            + s_c[2] * __expf(-s_a[2] * rzd)
            + s_c[3] * __expf(-s_a[3] * rzd);
    float sd = dist * (1.0f / 1.5f);
    float u1 = fmaxf(sd, 1e-8f);                    // dist>=0 -> == ternary
    float u2 = fmaxf(1.0f - sd, 1e-8f);
    float e_d  = __expf(-__builtin_amdgcn_rcpf(u1));
    float e_1d = __expf(-__builtin_amdgcn_rcpf(u2));
    float w = e_1d * __builtin_amdgcn_rcpf(e_1d + e_d);
    return 7.199822675975274f * w * x * y;          // KE/2 folded in
}

// ---- Pass 1: block-level counting-sort multisplit (512 thr, 8 waves) ----
// A: batched loads + 16 back-to-back u8 species gathers per thread, then
//    energies; LDS histogram atomic gives each record its rank (<4096).
// B: exclusive scan (t<256) + one global atomic per (block,bucket).
// C: scatter bucket-ordered into 32 KB LDS staging.
// D: linear coalesced write-out.
__global__ __launch_bounds__(512, 6) void zbl_bin_kernel(
    const float* __restrict__ distances,
    const float* __restrict__ cutoffs,
    const int* __restrict__ senders,
    const int* __restrict__ receivers,
    const unsigned char* __restrict__ sp8,
    const float* __restrict__ params,
    unsigned* __restrict__ cnt,
    uint2* __restrict__ pairs,
    int cap,
    float* __restrict__ out,
    int E)
{
    __shared__ float s_zf[SPECIES_CAP];
    __shared__ float s_zpd[SPECIES_CAP];
    __shared__ float s_a[4];
    __shared__ float s_c[4];
    __shared__ unsigned h_cnt[NB];     // histogram
    __shared__ unsigned h_lbase[NB];   // local exclusive base (scan)
    __shared__ unsigned h_gbase[NB];   // reserved global segment base
    __shared__ unsigned wtot[4];       // per-wave scan totals
    __shared__ unsigned s_total;
    __shared__ uint2 stg[TILE];        // 32 KB bucket-ordered staging
    int t = threadIdx.x;
    if (t < 4)              s_a[t]     = params[WS_A + t];
    else if (t < 8)         s_c[t - 4] = params[WS_C + (t - 4)];
    for (int s = t; s < SPECIES_CAP; s += BTHREADS) {
        s_zf[s]  = params[WS_ZF + s];
        s_zpd[s] = params[WS_ZPD + s];
    }
    if (t < NB) h_cnt[t] = 0u;
    __syncthreads();

    float    en[ITER];
    unsigned pk[ITER];                 // (rank<<20) | rcv ; rank<4096, rcv<2^20
    unsigned vmask = 0u;
    int sub = blockIdx.x & (NSUB - 1);
    int ebase = blockIdx.x * TILE;

    // ---- Phase A ----
    if (ebase + TILE <= E) {
        int   rr[ITER], sn[ITER];
        float dd[ITER], cc[ITER];
#pragma unroll
        for (int c = 0; c < CHUNK; ++c) {
            int vbase = ebase + (c * BTHREADS + t) * 4;
            float4 d4 = *(const float4*)(distances + vbase);
            float4 c4 = *(const float4*)(cutoffs + vbase);
            int4   s4 = *(const int4*)(senders + vbase);
            int4   r4 = *(const int4*)(receivers + vbase);
            rr[c*4+0] = r4.x; rr[c*4+1] = r4.y; rr[c*4+2] = r4.z; rr[c*4+3] = r4.w;
            sn[c*4+0] = s4.x; sn[c*4+1] = s4.y; sn[c*4+2] = s4.z; sn[c*4+3] = s4.w;
            dd[c*4+0] = d4.x; dd[c*4+1] = d4.y; dd[c*4+2] = d4.z; dd[c*4+3] = d4.w;
            cc[c*4+0] = c4.x; cc[c*4+1] = c4.y; cc[c*4+2] = c4.z; cc[c*4+3] = c4.w;
        }
        int spi[ITER], spj[ITER];
#pragma unroll
        for (int k = 0; k < ITER; ++k) {           // 16 independent gathers
            spi[k] = sp8[rr[k]];
            spj[k] = sp8[sn[k]];
        }
#pragma unroll
        for (int k = 0; k < ITER; ++k)
            en[k] = zbl_energy2(dd[k], cc[k], spi[k], spj[k],
                                s_zf, s_zpd, s_a, s_c);
#pragma unroll
        for (int k = 0; k < ITER; ++k) {
            unsigned b  = ((unsigned)rr[k]) >> RSHIFT;
            unsigned rk = atomicAdd(&h_cnt[b], 1u);
            pk[k] = (rk << 20) | (unsigned)rr[k];
        }
        vmask = (1u << ITER) - 1u;
    } else {
#pragma unroll
        for (int c = 0; c < CHUNK; ++c) {
#pragma unroll
            for (int k = 0; k < 4; ++k) {
                int e = ebase + (c * BTHREADS + t) * 4 + k;
                if (e < E) {
                    int rcv = receivers[e];
                    int si = sp8[rcv];
                    int sj = sp8[senders[e]];
                    en[c*4+k] = zbl_energy2(distances[e], cutoffs[e], si, sj,
                                            s_zf, s_zpd, s_a, s_c);
                    unsigned b  = ((unsigned)rcv) >> RSHIFT;
                    unsigned rk = atomicAdd(&h_cnt[b], 1u);
                    pk[c*4+k] = (rk << 20) | (unsigned)rcv;
                    vmask |= 1u << (c*4+k);
                }
            }
        }
    }
    __syncthreads();

    // ---- Phase B: exclusive scan over NB=256 buckets + global reserve ----
    if (t < NB) {
        unsigned orig = h_cnt[t];
        unsigned v = orig;
        int lane = t & 63;
#pragma unroll
        for (int d = 1; d < 64; d <<= 1) {
            unsigned nv = __shfl_up(v, d, 64);
            if (lane >= d) v += nv;
        }
        if (lane == 63) wtot[t >> 6] = v;
        __syncthreads();
        unsigned off = 0;
        int wid = t >> 6;
#pragma unroll
        for (int w = 0; w < 3; ++w)
            if (w < wid) off += wtot[w];
        unsigned incl = off + v;
        h_lbase[t] = incl - orig;
        h_gbase[t] = orig
            ? atomicAdd(&cnt[(t * NSUB + sub) * CNT_STRIDE], orig) : 0u;
        if (t == NB - 1) s_total = incl;
    } else {
        __syncthreads();
    }
    __syncthreads();

    // ---- Phase C: scatter bucket-ordered into LDS staging ----
#pragma unroll
    for (int k = 0; k < ITER; ++k) {
        if ((vmask >> k) & 1u) {
            unsigned u   = pk[k];
            unsigned rcv = u & 0xFFFFFu;
            unsigned rk  = u >> 20;
            unsigned b   = rcv >> RSHIFT;
            stg[h_lbase[b] + rk] = make_uint2(rcv, __float_as_uint(en[k]));
        }
    }
    __syncthreads();

    // ---- Phase D: linear coalesced write-out ----
    unsigned total = s_total;
    for (unsigned i = t; i < total; i += BTHREADS) {
        uint2 q = stg[i];
        unsigned b   = q.x >> RSHIFT;
        unsigned pos = h_gbase[b] + (i - h_lbase[b]);
        if (pos < (unsigned)cap)
            pairs[(size_t)(b * NSUB + sub) * cap + pos] = q;
        else
            unsafeAtomicAdd(out + q.x, __uint_as_float(q.y));  // overflow
    }
}

// ---- Pass 2: one block per sub-stream; LDS reduce; atomic flush ----
__global__ __launch_bounds__(256) void zbl_reduce_kernel(
    const unsigned* __restrict__ cnt,
    const uint2* __restrict__ pairs,
    int cap,
    float* __restrict__ out,
    int n_nodes)
{
    __shared__ float acc[RNODES];          // 16 KB
    int bs = blockIdx.x;                   // sub-stream id = b*NSUB+sub
    int b  = bs / NSUB;
    int t  = threadIdx.x;
    for (int i = t; i < RNODES; i += 256) acc[i] = 0.0f;
    __syncthreads();

    int entries = min((int)cnt[bs * CNT_STRIDE], cap);
    const uint2* pb  = pairs + (size_t)bs * cap;
    const uint4* pb4 = (const uint4*)pb;   // cap forced even -> aligned
    int n2 = entries >> 1;
    for (int j = t; j < n2; j += 256) {
        uint4 q = pb4[j];
        atomicAdd(&acc[q.x & (RNODES - 1)], __uint_as_float(q.y));
        atomicAdd(&acc[q.z & (RNODES - 1)], __uint_as_float(q.w));
    }
    if ((entries & 1) && t == 0) {
        uint2 pr = pb[entries - 1];
        atomicAdd(&acc[pr.x & (RNODES - 1)], __uint_as_float(pr.y));
    }
    __syncthreads();

    int nbase = b << RSHIFT;
    int nmax  = n_nodes - nbase;
    if (nmax <= 0) return;
    int lim = (nmax < RNODES) ? nmax : RNODES;
    for (int i = t; i < lim; i += 256) {
        float v = acc[i];
        if (v != 0.0f) unsafeAtomicAdd(out + nbase + i, v);
    }
}

// ---- Fallback: direct scattered atomics ----
__global__ __launch_bounds__(256) void zbl_direct_kernel(
    const float* __restrict__ distances,
    const float* __restrict__ cutoffs,
    const int* __restrict__ senders,
    const int* __restrict__ receivers,
    const int* __restrict__ node_species,
    const float* __restrict__ params,
    float* __restrict__ out,
    int E)
{
    __shared__ float s_zf[SPECIES_CAP];
    __shared__ float s_zpd[SPECIES_CAP];
    __shared__ float s_a[4];
    __shared__ float s_c[4];
    int t = threadIdx.x;
    if (t < 4)              s_a[t]     = params[WS_A + t];
    else if (t < 8)         s_c[t - 4] = params[WS_C + (t - 4)];
    for (int s = t; s < SPECIES_CAP; s += blockDim.x) {
        s_zf[s]  = params[WS_ZF + s];
        s_zpd[s] = params[WS_ZPD + s];
    }
    __syncthreads();
    int base = (blockIdx.x * 256 + t) * 4;
    int lim = min(base + 4, E);
    for (int e = base; e < lim; ++e) {
        int rcv = receivers[e];
        float en = zbl_energy2(distances[e], cutoffs[e],
                               node_species[rcv], node_species[senders[e]],
                               s_zf, s_zpd, s_a, s_c);
        unsafeAtomicAdd(out + rcv, en);
    }
}

extern "C" void kernel_launch(void* const* d_in, const int* in_sizes, int n_in,
                              void* d_out, int out_size, void* d_ws, size_t ws_size,
                              hipStream_t stream)
{
    const int*   node_species = (const int*)d_in[0];
    const float* distances    = (const float*)d_in[1];
    const float* cutoffs      = (const float*)d_in[2];
    const int*   senders      = (const int*)d_in[3];
    const int*   receivers    = (const int*)d_in[4];
    const int*   index_to_z   = (const int*)d_in[5];
    const float* a_raw        = (const float*)d_in[6];
    const float* c_raw        = (const float*)d_in[7];
    const float* p_raw        = (const float*)d_in[8];
    const float* d_raw        = (const float*)d_in[9];

    int E         = in_sizes[1];
    int n_species = in_sizes[5];
    int n_nodes   = in_sizes[0];
    float*    out    = (float*)d_out;
    float*    params = (float*)((char*)d_ws + PARAMS_OFF);
    unsigned* cnt    = (unsigned*)((char*)d_ws + CNT_OFF);

    // u8 species table after counters; pairs after that (4 KB aligned)
    size_t spec8_off   = CNT_OFF + CNT_BYTES;
    size_t spec8_bytes = ((size_t)n_nodes + 4095) & ~(size_t)4095;
    size_t pairs_off   = spec8_off + spec8_bytes;
    unsigned char* sp8 = (unsigned char*)d_ws + spec8_off;
    uint2* pairs       = (uint2*)((char*)d_ws + pairs_off);

    size_t avail = (ws_size > pairs_off) ? (ws_size - pairs_off) : 0;
    long long cap_ll = (long long)(avail / ((size_t)NB * NSUB * sizeof(uint2)));
    int want = E / (NB * NSUB) + E / (NB * NSUB * 4) + 1024;  // ~1.28x avg
    int cap = (int)((cap_ll < (long long)want) ? cap_ll : (long long)want);
    cap &= ~1;   // even -> uint4-aligned sub-stream reads in pass 2

    hipMemsetAsync(d_out, 0, (size_t)out_size * sizeof(float), stream);
    zbl_setup<<<1, 128, 0, stream>>>(a_raw, c_raw, p_raw, d_raw,
                                     index_to_z, n_species, params);

    // binned path needs rcv < 2^20 (pk packing) and species values < 256 (u8)
    if (cap >= 4096 && n_nodes <= (1 << 20) && n_species <= SPECIES_CAP) {
        hipMemsetAsync(cnt, 0, CNT_BYTES, stream);
        int pblocks = (n_nodes / 4 + 255) / 256 + 1;
        zbl_pack8<<<pblocks, 256, 0, stream>>>(node_species, sp8, n_nodes);
        int blocks = (E + TILE - 1) / TILE;
        zbl_bin_kernel<<<blocks, BTHREADS, 0, stream>>>(
            distances, cutoffs, senders, receivers, sp8,
            params, cnt, pairs, cap, out, E);
        zbl_reduce_kernel<<<NB * NSUB, 256, 0, stream>>>(
            cnt, pairs, cap, out, n_nodes);
    } else {
        int blocks = ((E + 3) / 4 + 255) / 256;
        zbl_direct_kernel<<<blocks, 256, 0, stream>>>(
            distances, cutoffs, senders, receivers, node_species,
            params, out, E);
    }
}